// Round 12
// baseline (48.551 us; speedup 1.0000x reference)
//
#include <hip/hip_runtime.h>

#define GSZ   64
#define G3    (GSZ * GSZ * GSZ)      // 262144
#define NCAM  8
#define NJ    23
#define IMW   1280
#define IMH   1024
#define HMW   (IMW / 2)              // 640
#define HMH   (IMH / 2)              // 512
#define HWSZ  (HMW * HMH)            // 327680
#define JG    4                      // joints per block; grid.y = ceil(23/4) = 6

__global__ __launch_bounds__(256) void reproj_kernel(
    const float* __restrict__ hm,      // [B, C, J, 512, 640]
    const float* __restrict__ center,  // [B, 3]
    const float* __restrict__ cam,     // [B, C, 4, 3]
    float* __restrict__ out)           // [B, J, 64, 64, 64]
{
#pragma clang fp contract(off)
    const int bid = blockIdx.x;
    const int b   = bid & 1;                          // batch<->XCD parity
    const int n   = (bid >> 1) * 256 + threadIdx.x;   // z-line waves: lane == z
    const int j0  = blockIdx.y * JG;                  // 0,4,8,12,16,20
    const int z = n & 63;
    const int y = (n >> 6) & 63;
    const int x = n >> 12;

    __shared__ float sM[NCAM * 12];
    if (threadIdx.x < NCAM * 12) {
        sM[threadIdx.x] = cam[b * NCAM * 12 + threadIdx.x];
    }
    __syncthreads();

    const float cx = center[b * 3 + 0];
    const float cy = center[b * 3 + 1];
    const float cz = center[b * 3 + 2];
    const float px = (float)(x - 32) * 2.0f + cx;
    const float py = (float)(y - 32) * 2.0f + cy;
    const float pz = (float)(z - 32) * 2.0f + cz;

    const float* __restrict__ hmb = hm + (size_t)b * NCAM * NJ * HWSZ;

    // ---- 8 projections -> flat offsets (camera base + my joint-group base) ----
    int off[NCAM];
#pragma unroll
    for (int c = 0; c < NCAM; ++c) {
        const float* M = &sM[c * 12];
        // XLA/Eigen ordering: sequential FMA along ascending k (bit-exact, R2-verified)
        float p0 = fmaf(pz, M[6], fmaf(py, M[3], px * M[0])) + M[9];
        float p1 = fmaf(pz, M[7], fmaf(py, M[4], px * M[1])) + M[10];
        float p2 = fmaf(pz, M[8], fmaf(py, M[5], px * M[2])) + M[11];
        float u = p0 / p2;              // IEEE divide (no fast-math)
        float v = p1 / p2;
        u = fminf(fmaxf(u, 0.0f), (float)(IMW - 1));
        v = fminf(fmaxf(v, 0.0f), (float)(IMH - 1));
        const int idx = (int)(v * 0.5f) * HMW + (int)(u * 0.5f);
        off[c] = c * (NJ * HWSZ) + j0 * HWSZ + idx;
    }

    const bool last = (j0 + 3 >= NJ);   // uniform: only group 5 (j0=20)
    const int  k3   = last ? 0 : 3;     // clamp 4th plane to stay in-bounds

    // ---- 32 independent gathers: 4 joint planes x 8 cameras ----
    float v0[NCAM], v1[NCAM], v2[NCAM], v3[NCAM];
#pragma unroll
    for (int c = 0; c < NCAM; ++c) {
        const float* p = hmb + off[c];
        v0[c] = p[0];
        v1[c] = p[HWSZ];
        v2[c] = p[2 * HWSZ];
        v3[c] = p[k3 * HWSZ];
    }

    // camera-ascending accumulation (bit-exact order, R2-verified)
    float a0 = 0.f, a1 = 0.f, a2 = 0.f, a3 = 0.f;
#pragma unroll
    for (int c = 0; c < NCAM; ++c) {
        a0 += v0[c]; a1 += v1[c]; a2 += v2[c]; a3 += v3[c];
    }

    float* ob = out + (size_t)b * NJ * G3 + (size_t)j0 * G3 + n;
    ob[0]          = a0 * 0.125f;
    ob[G3]         = a1 * 0.125f;
    ob[2 * (size_t)G3] = a2 * 0.125f;
    if (!last) ob[3 * (size_t)G3] = a3 * 0.125f;
}

extern "C" void kernel_launch(void* const* d_in, const int* in_sizes, int n_in,
                              void* d_out, int out_size, void* d_ws, size_t ws_size,
                              hipStream_t stream) {
    const float* hm     = (const float*)d_in[0];
    const float* center = (const float*)d_in[1];
    const float* cam    = (const float*)d_in[2];
    float* out          = (float*)d_out;

    dim3 grid((G3 / 256) * 2, (NJ + JG - 1) / JG, 1);  // 2048 x 6
    dim3 block(256, 1, 1);
    reproj_kernel<<<grid, block, 0, stream>>>(hm, center, cam, out);
}

// Round 13
// 47.280 us; speedup vs baseline: 1.0269x; 1.0269x over previous
//
#include <hip/hip_runtime.h>

#define GSZ   64
#define G3    (GSZ * GSZ * GSZ)      // 262144
#define NCAM  8
#define NJ    23
#define IMW   1280
#define IMH   1024
#define HMW   (IMW / 2)              // 640
#define HMH   (IMH / 2)              // 512
#define HWSZ  (HMW * HMH)            // 327680
#define RMAX  32                     // packed-path cap on distinct runs/wave
#define TMAX  ((RMAX * NJ + 63) / 64)  // 12 packed gather rounds max

__global__ __launch_bounds__(256) void reproj_kernel(
    const float* __restrict__ hm,      // [B, C, J, 512, 640]
    const float* __restrict__ center,  // [B, 3]
    const float* __restrict__ cam,     // [B, C, 4, 3]
    float* __restrict__ out)           // [B, J, 64, 64, 64]
{
#pragma clang fp contract(off)
    // XCD slab partitioning: round-robin dispatch puts block bid on XCD bid&7.
    // Batch = parity (as before); each XCD additionally owns a CONTIGUOUS
    // 256-chunk slab (16 x-planes) -> per-XCD L2 footprint ~4x smaller.
    const int bid   = blockIdx.x;
    const int b     = bid & 1;
    const int slab  = (bid >> 1) & 3;                  // which quarter of the volume
    const int chunk = slab * 256 + (bid >> 3);         // contiguous within XCD
    const int n     = chunk * 256 + threadIdx.x;       // z-line waves: lane == z
    const int z = n & 63;
    const int y = (n >> 6) & 63;
    const int x = n >> 12;
    const int lane = threadIdx.x & 63;
    const int wv   = threadIdx.x >> 6;

    __shared__ float sM[NCAM * 12];
    __shared__ int   sOff[4][RMAX];                    // per-wave deduped offsets
    __shared__ __align__(16) float sStage[4][RMAX * 24]; // [run][joint(+pad)]

    if (threadIdx.x < NCAM * 12) {
        sM[threadIdx.x] = cam[b * NCAM * 12 + threadIdx.x];
    }
    __syncthreads();

    const float cx = center[b * 3 + 0];
    const float cy = center[b * 3 + 1];
    const float cz = center[b * 3 + 2];
    const float px = (float)(x - 32) * 2.0f + cx;
    const float py = (float)(y - 32) * 2.0f + cy;
    const float pz = (float)(z - 32) * 2.0f + cz;

    const float* __restrict__ hmb = hm + (size_t)b * NCAM * NJ * HWSZ;

    // ---- projections + per-camera wave dedup ----
    int off[NCAM], runix[NCAM], Rcnt[NCAM];
    unsigned ldrbits = 0;
#pragma unroll
    for (int c = 0; c < NCAM; ++c) {
        const float* M = &sM[c * 12];
        // XLA/Eigen ordering: sequential FMA along ascending k (bit-exact, R2-verified)
        float p0 = fmaf(pz, M[6], fmaf(py, M[3], px * M[0])) + M[9];
        float p1 = fmaf(pz, M[7], fmaf(py, M[4], px * M[1])) + M[10];
        float p2 = fmaf(pz, M[8], fmaf(py, M[5], px * M[2])) + M[11];
        float u = p0 / p2;              // IEEE divide (no fast-math)
        float v = p1 / p2;
        u = fminf(fmaxf(u, 0.0f), (float)(IMW - 1));
        v = fminf(fmaxf(v, 0.0f), (float)(IMH - 1));
        const int idx = (int)(v * 0.5f) * HMW + (int)(u * 0.5f);
        off[c] = c * (NJ * HWSZ) + idx;

        const int  prev  = __shfl_up(idx, 1);
        const bool start = (lane == 0) || (idx != prev);
        const unsigned long long mask = __ballot(start);
        runix[c] = __popcll(mask & ((2ull << lane) - 1ull)) - 1;
        Rcnt[c]  = __popcll(mask);
        ldrbits |= ((unsigned)start) << c;
    }

    // ---- camera-invariant per-round indices ----
    int rr[TMAX], jHW[TMAX], sAd[TMAX];
#pragma unroll
    for (int t = 0; t < TMAX; ++t) {
        const int p = t * 64 + lane;
        const int r = (int)((unsigned)p / 23u);
        const int j = p - r * 23;
        rr[t]  = r;
        jHW[t] = j * HWSZ;
        sAd[t] = r * 24 + j;
    }

    float acc[NJ];
#pragma unroll
    for (int j = 0; j < NJ; ++j) acc[j] = 0.0f;

#pragma unroll
    for (int c = 0; c < NCAM; ++c) {
        const int R     = Rcnt[c];
        const int myrun = runix[c];
        if (R <= RMAX) {
            // leaders publish deduped offsets (same-wave DS ops are in-order)
            if ((ldrbits >> c) & 1u) sOff[wv][myrun] = off[c];
            const int vcnt = R * NJ;

            // A1: fetch round offsets from LDS (all reads issue together)
            int po[TMAX];
#pragma unroll
            for (int t = 0; t < TMAX; ++t) {
                if (t * 64 + lane < vcnt) po[t] = sOff[wv][rr[t]];
            }
            // A2: packed gathers — all 64 lanes fetch distinct (run,joint) values
            float val[TMAX];
#pragma unroll
            for (int t = 0; t < TMAX; ++t) {
                if (t * 64 + lane < vcnt) val[t] = hmb[po[t] + jHW[t]];
            }
            // B: stage into LDS [run][joint]
#pragma unroll
            for (int t = 0; t < TMAX; ++t) {
                if (t * 64 + lane < vcnt) sStage[wv][sAd[t]] = val[t];
            }
            // C: vectorized read-back of my run's 23 joints
            const float4* s4 = (const float4*)&sStage[wv][myrun * 24];
            const float4 a0 = s4[0], a1 = s4[1], a2 = s4[2], a3 = s4[3], a4 = s4[4];
            const float2 a5 = *(const float2*)&sStage[wv][myrun * 24 + 20];
            const float  a6 = sStage[wv][myrun * 24 + 22];
            acc[ 0] += a0.x; acc[ 1] += a0.y; acc[ 2] += a0.z; acc[ 3] += a0.w;
            acc[ 4] += a1.x; acc[ 5] += a1.y; acc[ 6] += a1.z; acc[ 7] += a1.w;
            acc[ 8] += a2.x; acc[ 9] += a2.y; acc[10] += a2.z; acc[11] += a2.w;
            acc[12] += a3.x; acc[13] += a3.y; acc[14] += a3.z; acc[15] += a3.w;
            acc[16] += a4.x; acc[17] += a4.y; acc[18] += a4.z; acc[19] += a4.w;
            acc[20] += a5.x; acc[21] += a5.y; acc[22] += a6;
        } else {
            // rare high-diversity wave: plain per-lane gather
            const int o = off[c];
#pragma unroll
            for (int j = 0; j < NJ; ++j) acc[j] += hmb[o + j * HWSZ];
        }
    }

    float* ob = out + (size_t)b * NJ * G3 + n;
#pragma unroll
    for (int j = 0; j < NJ; ++j) {
        ob[(size_t)j * G3] = acc[j] * 0.125f;
    }
}

extern "C" void kernel_launch(void* const* d_in, const int* in_sizes, int n_in,
                              void* d_out, int out_size, void* d_ws, size_t ws_size,
                              hipStream_t stream) {
    const float* hm     = (const float*)d_in[0];
    const float* center = (const float*)d_in[1];
    const float* cam    = (const float*)d_in[2];
    float* out          = (float*)d_out;

    dim3 grid((G3 / 256) * 2, 1, 1);   // bid&7 = XCD under round-robin dispatch
    dim3 block(256, 1, 1);
    reproj_kernel<<<grid, block, 0, stream>>>(hm, center, cam, out);
}

// Round 14
// 43.666 us; speedup vs baseline: 1.1119x; 1.0828x over previous
//
#include <hip/hip_runtime.h>

#define GSZ   64
#define G3    (GSZ * GSZ * GSZ)      // 262144
#define NCAM  8
#define NJ    23
#define IMW   1280
#define IMH   1024
#define HMW   (IMW / 2)              // 640
#define HMH   (IMH / 2)              // 512
#define HWSZ  (HMW * HMH)            // 327680
#define RMAX  32                     // packed-path cap on distinct runs/wave
#define NPAIR 12                     // joint-pairs per run: (0,1)..(22,pad)
#define TMAX  ((RMAX * NPAIR) / 64)  // 6 packed rounds (32*12 = 384 = 6*64 exact)

__global__ __launch_bounds__(256) void reproj_kernel(
    const float* __restrict__ hm,      // [B, C, J, 512, 640]
    const float* __restrict__ center,  // [B, 3]
    const float* __restrict__ cam,     // [B, C, 4, 3]
    float* __restrict__ out)           // [B, J, 64, 64, 64]
{
#pragma clang fp contract(off)
    const int bid  = blockIdx.x;
    const int b    = bid & 1;                          // batch<->XCD parity
    const int n    = (bid >> 1) * 256 + threadIdx.x;   // z-line waves: lane == z
    const int z = n & 63;
    const int y = (n >> 6) & 63;
    const int x = n >> 12;
    const int lane = threadIdx.x & 63;
    const int wv   = threadIdx.x >> 6;

    __shared__ float sM[NCAM * 12];
    __shared__ int   sOff[4][RMAX];                    // per-wave deduped offsets
    __shared__ __align__(16) float sStage[4][RMAX * 24]; // [run][joint(+pad)]

    if (threadIdx.x < NCAM * 12) {
        sM[threadIdx.x] = cam[b * NCAM * 12 + threadIdx.x];
    }
    __syncthreads();

    const float cx = center[b * 3 + 0];
    const float cy = center[b * 3 + 1];
    const float cz = center[b * 3 + 2];
    const float px = (float)(x - 32) * 2.0f + cx;
    const float py = (float)(y - 32) * 2.0f + cy;
    const float pz = (float)(z - 32) * 2.0f + cz;

    const float* __restrict__ hmb = hm + (size_t)b * NCAM * NJ * HWSZ;

    // ---- projections + per-camera wave dedup ----
    int off[NCAM], runix[NCAM], Rcnt[NCAM];
    unsigned ldrbits = 0;
#pragma unroll
    for (int c = 0; c < NCAM; ++c) {
        const float* M = &sM[c * 12];
        // XLA/Eigen ordering: sequential FMA along ascending k (bit-exact, R2-verified)
        float p0 = fmaf(pz, M[6], fmaf(py, M[3], px * M[0])) + M[9];
        float p1 = fmaf(pz, M[7], fmaf(py, M[4], px * M[1])) + M[10];
        float p2 = fmaf(pz, M[8], fmaf(py, M[5], px * M[2])) + M[11];
        float u = p0 / p2;              // IEEE divide (no fast-math)
        float v = p1 / p2;
        u = fminf(fmaxf(u, 0.0f), (float)(IMW - 1));
        v = fminf(fmaxf(v, 0.0f), (float)(IMH - 1));
        const int idx = (int)(v * 0.5f) * HMW + (int)(u * 0.5f);
        off[c] = c * (NJ * HWSZ) + idx;

        const int  prev  = __shfl_up(idx, 1);
        const bool start = (lane == 0) || (idx != prev);
        const unsigned long long mask = __ballot(start);
        runix[c] = __popcll(mask & ((2ull << lane) - 1ull)) - 1;
        Rcnt[c]  = __popcll(mask);
        ldrbits |= ((unsigned)start) << c;
    }

    // ---- camera-invariant per-round indices (pair-packed: slot -> (run, jpair)) ----
    int rr[TMAX], j0HW[TMAX], j1HW[TMAX], sAd[TMAX];
#pragma unroll
    for (int t = 0; t < TMAX; ++t) {
        const unsigned p  = t * 64 + lane;           // pair-slot index, 0..383
        const int r  = (int)(p / 12u);
        const int jp = (int)(p % 12u);
        rr[t]   = r;
        j0HW[t] = (2 * jp) * HWSZ;
        j1HW[t] = (jp == 11 ? 22 : 2 * jp + 1) * HWSZ;  // pad pair re-reads plane 22 (no OOB)
        sAd[t]  = r * 24 + 2 * jp;
    }

    float acc[NJ];
#pragma unroll
    for (int j = 0; j < NJ; ++j) acc[j] = 0.0f;

#pragma unroll
    for (int c = 0; c < NCAM; ++c) {
        const int R     = Rcnt[c];
        const int myrun = runix[c];
        if (R <= RMAX) {
            // leaders publish deduped offsets (same-wave DS ops are in-order)
            if ((ldrbits >> c) & 1u) sOff[wv][myrun] = off[c];
            const int pcnt = R * NPAIR;

            // A1: one offset read per PAIR-slot (6 ds_read, half of R6)
            int po[TMAX];
#pragma unroll
            for (int t = 0; t < TMAX; ++t) {
                if (t * 64 + lane < pcnt) po[t] = sOff[wv][rr[t]];
            }
            // A2: packed gathers — 2 planes per slot (12 loads, same as R6)
            float v0[TMAX], v1[TMAX];
#pragma unroll
            for (int t = 0; t < TMAX; ++t) {
                if (t * 64 + lane < pcnt) {
                    v0[t] = hmb[po[t] + j0HW[t]];
                    v1[t] = hmb[po[t] + j1HW[t]];
                }
            }
            // B: stage pairs as b64 (6 ds_write, half of R6)
#pragma unroll
            for (int t = 0; t < TMAX; ++t) {
                if (t * 64 + lane < pcnt) {
                    *(float2*)&sStage[wv][sAd[t]] = make_float2(v0[t], v1[t]);
                }
            }
            // C: vectorized read-back of my run's 23 joints
            const float4* s4 = (const float4*)&sStage[wv][myrun * 24];
            const float4 a0 = s4[0], a1 = s4[1], a2 = s4[2], a3 = s4[3], a4 = s4[4];
            const float4 a5 = s4[5];                      // .w = pad, ignored
            acc[ 0] += a0.x; acc[ 1] += a0.y; acc[ 2] += a0.z; acc[ 3] += a0.w;
            acc[ 4] += a1.x; acc[ 5] += a1.y; acc[ 6] += a1.z; acc[ 7] += a1.w;
            acc[ 8] += a2.x; acc[ 9] += a2.y; acc[10] += a2.z; acc[11] += a2.w;
            acc[12] += a3.x; acc[13] += a3.y; acc[14] += a3.z; acc[15] += a3.w;
            acc[16] += a4.x; acc[17] += a4.y; acc[18] += a4.z; acc[19] += a4.w;
            acc[20] += a5.x; acc[21] += a5.y; acc[22] += a5.z;
        } else {
            // rare high-diversity wave: plain per-lane gather
            const int o = off[c];
#pragma unroll
            for (int j = 0; j < NJ; ++j) acc[j] += hmb[o + j * HWSZ];
        }
    }

    float* ob = out + (size_t)b * NJ * G3 + n;
#pragma unroll
    for (int j = 0; j < NJ; ++j) {
        ob[(size_t)j * G3] = acc[j] * 0.125f;
    }
}

extern "C" void kernel_launch(void* const* d_in, const int* in_sizes, int n_in,
                              void* d_out, int out_size, void* d_ws, size_t ws_size,
                              hipStream_t stream) {
    const float* hm     = (const float*)d_in[0];
    const float* center = (const float*)d_in[1];
    const float* cam    = (const float*)d_in[2];
    float* out          = (float*)d_out;

    dim3 grid((G3 / 256) * 2, 1, 1);   // (n-chunk, batch) interleaved on bit 0
    dim3 block(256, 1, 1);
    reproj_kernel<<<grid, block, 0, stream>>>(hm, center, cam, out);
}